// Round 11
// baseline (170.448 us; speedup 1.0000x reference)
//
#include <hip/hip_runtime.h>

// NodeBlock: agg = segment_sum(edges[1.6M,64], recv -> 50000 nodes)
//            X = [agg] only; nodes read directly by mlp; globals in bias
//            out = relu([agg|nodes]@W1[:192]+b1') @ W2 + b2  (f32, 50000x128)
//
// R30 = R29 (153.3 us measured) + scatter occupancy fix: EPB 4096->2048
// (782 blocks = 3/CU, 12 waves/CU vs 1.5/CU; per-thread chain 16->8 edges).
// Scatter is the only dispatch far above its traffic floor (15 us vs 2 us
// of BW) -> latency/occupancy-bound. Parameter-only change, same CAP margin.
// R29 ledger (est): gather 80 (random-read floor) | mlp 31 (accepted,
// 3 strikes) | scatter 15 | prep 3 | gaps ~20.

typedef __bf16 bf16x8 __attribute__((ext_vector_type(8)));
typedef __bf16 bf16x4 __attribute__((ext_vector_type(4)));
typedef __bf16 bf16x2 __attribute__((ext_vector_type(2)));
typedef float f32x4 __attribute__((ext_vector_type(4)));
typedef int i32x4 __attribute__((ext_vector_type(4)));

#define EDGE_DIM 64
#define NODE_DIM 128
#define XDIM 192     // logical MLP K: agg(64) | nodes(128)
#define HID_DIM 256
#define OUT_DIM 128
#define NBUCKET 2048
#define NPB 25       // nodes per bucket: 2048*25 = 51200 >= 50000; local < 32 (5 bits)
#define CAP 1024     // bucket capacity (mean 781, sigma ~28 -> 8.7 sigma margin)
#define EPB 2048     // edges per scatter block (256 thr x 8)
#define MT 64        // M-tile of MLP
#define HPAD 280     // Hs row stride (bf16)

// ---------------- K1: weight prep (+bias fold) + gcur init ------------------
__global__ __launch_bounds__(256) void prep_kernel(
    const float* __restrict__ W1, const float* __restrict__ b1,
    const float* __restrict__ W2, const float* __restrict__ glob,
    __bf16* __restrict__ W1T, float* __restrict__ b1f, __bf16* __restrict__ W2T,
    int* __restrict__ gcur) {
  const int b = blockIdx.x, t = threadIdx.x;
  if (b < HID_DIM) {
    if (t < XDIM) {
      W1T[b * XDIM + t] = (__bf16)W1[t * HID_DIM + b];
    } else {
      // threads 192..255 == wave 3: fold globals into bias (f32 exact)
      float p = glob[t - XDIM] * W1[t * HID_DIM + b];
      for (int off = 32; off; off >>= 1) p += __shfl_xor(p, off, 64);
      if (t == XDIM) b1f[b] = b1[b] + p;
    }
    return;
  }
  if (b < HID_DIM + OUT_DIM) {
    int nn = b - HID_DIM;
    W2T[nn * HID_DIM + t] = (__bf16)W2[t * OUT_DIM + nn];
    return;
  }
  // b == HID_DIM + OUT_DIM: init bucket cursors to fixed bases
  for (int k = t; k < NBUCKET; k += 256) gcur[k] = k * CAP;
}

// ---------------- K2: fused count + reserve + scatter -----------------------
__global__ __launch_bounds__(256) void scatter_kernel(
    const int* __restrict__ recv, int* __restrict__ gcur,
    int* __restrict__ sorted1, int n_edges) {
  const int kb = blockIdx.x, t = threadIdx.x;
  __shared__ int h[NBUCKET];  // pass 1: counts; pass 2: cursors (8 KB)
  for (int k = t; k < NBUCKET; k += 256) h[k] = 0;
  __syncthreads();

  const int i0 = kb * EPB + t * 8;
  int rr[8];
  int bk[8];
  if (i0 + 8 <= n_edges) {
#pragma unroll
    for (int c = 0; c < 2; ++c) {
      i32x4 r4 = *(const i32x4*)(recv + i0 + c * 4);
      rr[c * 4 + 0] = r4.x; rr[c * 4 + 1] = r4.y;
      rr[c * 4 + 2] = r4.z; rr[c * 4 + 3] = r4.w;
    }
  } else {
#pragma unroll
    for (int j = 0; j < 8; ++j) rr[j] = (i0 + j < n_edges) ? recv[i0 + j] : -1;
  }
#pragma unroll
  for (int j = 0; j < 8; ++j) {
    bk[j] = (rr[j] >= 0) ? (rr[j] / NPB) : -1;
    if (bk[j] >= 0) atomicAdd(&h[bk[j]], 1);
  }
  __syncthreads();

  // reserve this block's segment in each touched bucket (global atomic)
  for (int k = t; k < NBUCKET; k += 256) {
    int c = h[k];
    h[k] = (c > 0) ? atomicAdd(&gcur[k], c) : 0;  // overwrite count with base
  }
  __syncthreads();

  // scatter: cursor = LDS base, packed payload (eid<<5)|local
#pragma unroll
  for (int j = 0; j < 8; ++j) {
    if (bk[j] >= 0) {
      const int p = atomicAdd(&h[bk[j]], 1);
      sorted1[p] = ((i0 + j) << 5) | (rr[j] - bk[j] * NPB);
    }
  }
}

// ---------------- K3: FUSED regroup (LDS) + quarter-wave gather -------------
#define NTLOAD(i) __builtin_nontemporal_load((const f32x4*)(edges + (size_t)(i) * EDGE_DIM + l15 * 4))

__global__ __launch_bounds__(256) void regroup_gather_kernel(
    const int* __restrict__ sorted1, const int* __restrict__ gcur,
    const float* __restrict__ edges,
    __bf16* __restrict__ Xagg, int n_nodes) {
  const int b = blockIdx.x, t = threadIdx.x;
  __shared__ int eidl[CAP];      // 4 KB: per-node-grouped eids (bucket-local)
  __shared__ int loff[NPB + 1];
  __shared__ int cnt[NPB];
  if (t < NPB) cnt[t] = 0;
  __syncthreads();
  const int s = b * CAP, e = gcur[b];  // gcur holds bucket end
  // phase A1: count locals
  for (int j = s + t; j < e; j += 256) atomicAdd(&cnt[sorted1[j] & 31], 1);
  __syncthreads();
  if (t == 0) {
    int run = 0;
#pragma unroll
    for (int k = 0; k < NPB; ++k) { loff[k] = run; run += cnt[k]; }
    loff[NPB] = run;
  }
  __syncthreads();
  if (t < NPB) cnt[t] = 0;  // reuse as cursor
  __syncthreads();
  // phase A2: group eids into LDS
  for (int j = s + t; j < e; j += 256) {
    const int p = sorted1[j];
    const int local = p & 31;
    const int slot = atomicAdd(&cnt[local], 1);
    eidl[loff[local] + slot] = p >> 5;
  }
  __syncthreads();

  // phase B: gather — wave w owns locals w, w+4, ... (proven 4-deep pipeline)
  const int wave = t >> 6;
  const int lane = t & 63;
  const int q = lane >> 4;
  const int l15 = lane & 15;
  for (int local = wave; local < NPB; local += 4) {
    const int node = b * NPB + local;
    if (node >= n_nodes) break;
    const int ls = loff[local];
    const int le = loff[local + 1];
    f32x4 a0 = {0.f, 0.f, 0.f, 0.f}, a1 = a0, a2 = a0, a3 = a0;

    int j = ls + q;
    int i0 = (j < le) ? eidl[j] : 0;
    int i1 = (j + 4 < le) ? eidl[j + 4] : 0;
    int i2 = (j + 8 < le) ? eidl[j + 8] : 0;
    int i3 = (j + 12 < le) ? eidl[j + 12] : 0;

    while (j + 12 < le) {
      f32x4 v0 = NTLOAD(i0);
      f32x4 v1 = NTLOAD(i1);
      f32x4 v2 = NTLOAD(i2);
      f32x4 v3 = NTLOAD(i3);
      int n0 = (j + 16 < le) ? eidl[j + 16] : 0;
      int n1 = (j + 20 < le) ? eidl[j + 20] : 0;
      int n2 = (j + 24 < le) ? eidl[j + 24] : 0;
      int n3 = (j + 28 < le) ? eidl[j + 28] : 0;
      a0 += v0; a1 += v1; a2 += v2; a3 += v3;
      i0 = n0; i1 = n1; i2 = n2; i3 = n3;
      j += 16;
    }
    if (j < le)     a0 += NTLOAD(i0);
    if (j + 4 < le) a1 += NTLOAD(i1);
    if (j + 8 < le) a2 += NTLOAD(i2);

    a0 += a1; a2 += a3; a0 += a2;
#pragma unroll
    for (int c = 0; c < 4; ++c) {  // reduce across the 4 quarters
      float v = a0[c];
      v += __shfl_xor(v, 16, 64);
      v += __shfl_xor(v, 32, 64);
      a0[c] = v;
    }
    if (q == 0) {
      bf16x4 o;
      o[0] = (__bf16)a0[0]; o[1] = (__bf16)a0[1];
      o[2] = (__bf16)a0[2]; o[3] = (__bf16)a0[3];
      *(bf16x4*)(Xagg + (size_t)node * EDGE_DIM + l15 * 4) = o;  // 8B store
    }
  }
}

// ---------------- K4: fused MLP (nodes read direct, f32->bf16 in-reg) -------
__global__ __launch_bounds__(256, 2) void mlp_kernel(
    const __bf16* __restrict__ Xagg, const float* __restrict__ nodes,
    const __bf16* __restrict__ W1T, const float* __restrict__ b1f,
    const __bf16* __restrict__ W2T, const float* __restrict__ b2,
    float* __restrict__ out, int M) {
  __shared__ __bf16 Hs[MT][HPAD];
  const int wave = threadIdx.x >> 6;
  const int lane = threadIdx.x & 63;
  const int l15 = lane & 15;
  const int lk = lane >> 4;
  const int Mbase0 = blockIdx.x * MT;

  {  // phase 1: H = relu([Xagg|nodes] @ W1[:192] + b1') -> LDS (K=192)
    bf16x8 B1[4][6];
    float bias1[4];
    const int colbase = wave * 64;
#pragma unroll
    for (int cb = 0; cb < 4; ++cb) {
      const int col = colbase + cb * 16 + l15;
      const __bf16* wrow = W1T + col * XDIM + lk * 8;
#pragma unroll
      for (int ks = 0; ks < 6; ++ks) B1[cb][ks] = *(const bf16x8*)(wrow + ks * 32);
      bias1[cb] = b1f[col];
    }
#pragma unroll
    for (int mb = 0; mb < 4; ++mb) {
      const int Mbase = Mbase0 + mb * 16;
      const int arow = (Mbase + l15 < M) ? (Mbase + l15) : (M - 1);  // clamp
      f32x4 acc[4];
#pragma unroll
      for (int cb = 0; cb < 4; ++cb) {
        f32x4 ini = {bias1[cb], bias1[cb], bias1[cb], bias1[cb]};
        acc[cb] = ini;
      }
      const __bf16* xrow = Xagg + (size_t)arow * EDGE_DIM + lk * 8;
      const float* nrow = nodes + (size_t)arow * NODE_DIM + lk * 8;
      // ks 0..1: agg fragment from Xagg (bf16)
#pragma unroll
      for (int ks = 0; ks < 2; ++ks) {
        bf16x8 A = *(const bf16x8*)(xrow + ks * 32);
#pragma unroll
        for (int cb = 0; cb < 4; ++cb)
          acc[cb] = __builtin_amdgcn_mfma_f32_16x16x32_bf16(A, B1[cb][ks], acc[cb], 0, 0, 0);
      }
      // ks 2..5: node fragment from nodes (f32 -> bf16 in-register)
#pragma unroll
      for (int ks = 2; ks < 6; ++ks) {
        f32x4 n0 = *(const f32x4*)(nrow + (ks - 2) * 32);
        f32x4 n1 = *(const f32x4*)(nrow + (ks - 2) * 32 + 4);
        bf16x8 A;
        A[0] = (__bf16)n0[0]; A[1] = (__bf16)n0[1];
        A[2] = (__bf16)n0[2]; A[3] = (__bf16)n0[3];
        A[4] = (__bf16)n1[0]; A[5] = (__bf16)n1[1];
        A[6] = (__bf16)n1[2]; A[7] = (__bf16)n1[3];
#pragma unroll
        for (int cb = 0; cb < 4; ++cb)
          acc[cb] = __builtin_amdgcn_mfma_f32_16x16x32_bf16(A, B1[cb][ks], acc[cb], 0, 0, 0);
      }
#pragma unroll
      for (int cb = 0; cb < 4; ++cb) {
#pragma unroll
        for (int r = 0; r < 4; ++r) {
          float v = acc[cb][r];
          Hs[mb * 16 + lk * 4 + r][colbase + cb * 16 + l15] = (__bf16)(v > 0.f ? v : 0.f);
        }
      }
    }
  }
  __syncthreads();
  {  // phase 2: out = H @ W2 + b2
    bf16x8 B2[2][8];
    float bias2[2];
    const int colbase = wave * 32;
#pragma unroll
    for (int cb = 0; cb < 2; ++cb) {
      const int col = colbase + cb * 16 + l15;
      const __bf16* wrow = W2T + col * HID_DIM + lk * 8;
#pragma unroll
      for (int ks = 0; ks < 8; ++ks) B2[cb][ks] = *(const bf16x8*)(wrow + ks * 32);
      bias2[cb] = b2[col];
    }
#pragma unroll
    for (int mb = 0; mb < 4; ++mb) {
      const int Mbase = Mbase0 + mb * 16;
      f32x4 acc[2];
#pragma unroll
      for (int cb = 0; cb < 2; ++cb) {
        f32x4 ini = {bias2[cb], bias2[cb], bias2[cb], bias2[cb]};
        acc[cb] = ini;
      }
#pragma unroll
      for (int ks = 0; ks < 8; ++ks) {
        bf16x8 A = *(const bf16x8*)(&Hs[mb * 16 + l15][lk * 8 + ks * 32]);
#pragma unroll
        for (int cb = 0; cb < 2; ++cb)
          acc[cb] = __builtin_amdgcn_mfma_f32_16x16x32_bf16(A, B2[cb][ks], acc[cb], 0, 0, 0);
      }
#pragma unroll
      for (int cb = 0; cb < 2; ++cb) {
        const int col = colbase + cb * 16 + l15;
#pragma unroll
        for (int r = 0; r < 4; ++r) {
          const int row = Mbase + lk * 4 + r;
          if (row < M) out[(size_t)row * OUT_DIM + col] = acc[cb][r];
        }
      }
    }
  }
}

extern "C" void kernel_launch(void* const* d_in, const int* in_sizes, int n_in,
                              void* d_out, int out_size, void* d_ws, size_t ws_size,
                              hipStream_t stream) {
  const float* edges    = (const float*)d_in[0];
  const int*   recv     = (const int*)d_in[1];
  const float* nodes    = (const float*)d_in[2];
  const float* globals_ = (const float*)d_in[3];
  const float* W1       = (const float*)d_in[5];
  const float* b1       = (const float*)d_in[6];
  const float* W2       = (const float*)d_in[7];
  const float* b2       = (const float*)d_in[8];

  const int n_edges = in_sizes[0] / EDGE_DIM;  // 1600000
  const int n_nodes = in_sizes[2] / NODE_DIM;  // 50000
  const int NBH = (n_edges + EPB - 1) / EPB;   // 782 scatter blocks
  float* out = (float*)d_out;

  // workspace layout (~15 MB)
  char* ws = (char*)d_ws;
  size_t off = 0;
  int* gcur = (int*)(ws + off);    off += NBUCKET * 4;
  off = (off + 255) & ~(size_t)255;
  int* sorted1 = (int*)(ws + off); off += (size_t)NBUCKET * CAP * 4;  // 8 MB
  off = (off + 255) & ~(size_t)255;
  __bf16* Xagg = (__bf16*)(ws + off); off += (size_t)n_nodes * EDGE_DIM * 2;  // 6.4 MB
  off = (off + 255) & ~(size_t)255;
  __bf16* W1T = (__bf16*)(ws + off); off += (size_t)HID_DIM * XDIM * 2;
  off = (off + 255) & ~(size_t)255;
  float* b1f = (float*)(ws + off);  off += HID_DIM * 4;
  off = (off + 255) & ~(size_t)255;
  __bf16* W2T = (__bf16*)(ws + off); off += (size_t)HID_DIM * OUT_DIM * 2;

  prep_kernel<<<HID_DIM + OUT_DIM + 1, 256, 0, stream>>>(
      W1, b1, W2, globals_, W1T, b1f, W2T, gcur);
  scatter_kernel<<<NBH, 256, 0, stream>>>(recv, gcur, sorted1, n_edges);
  regroup_gather_kernel<<<NBUCKET, 256, 0, stream>>>(sorted1, gcur, edges,
                                                     Xagg, n_nodes);
  mlp_kernel<<<(n_nodes + MT - 1) / MT, 256, 0, stream>>>(Xagg, nodes, W1T, b1f,
                                                          W2T, b2, out, n_nodes);
}

// Round 12
// 154.694 us; speedup vs baseline: 1.1018x; 1.1018x over previous
//
#include <hip/hip_runtime.h>

// NodeBlock: agg = segment_sum(edges[1.6M,64], recv -> 50000 nodes)
//            X = [agg] only; nodes read directly by mlp; globals in bias
//            out = relu([agg|nodes]@W1[:192]+b1') @ W2 + b2  (f32, 50000x128)
//
// R31 = exact revert to R29 (best measured: 153.3 us). R30 (EPB 2048)
// regressed +17 us: scatter cost is per-block NBUCKET-fixed (LDS zero +
// reserve pass), so 2x blocks = 2x fixed overhead. EPB=4096 is the measured
// optimum; both directions of the axis are now closed.
// Final ledger: gather ~80 (410 MB random-read floor @ 5.2 TB/s) |
// mlp ~31 (latency-bound, 3 restructures failed) | scatter ~15 | prep ~3 |
// gaps ~24 (graph-capture-hidden per R27). Plateau declared.

typedef __bf16 bf16x8 __attribute__((ext_vector_type(8)));
typedef __bf16 bf16x4 __attribute__((ext_vector_type(4)));
typedef __bf16 bf16x2 __attribute__((ext_vector_type(2)));
typedef float f32x4 __attribute__((ext_vector_type(4)));
typedef int i32x4 __attribute__((ext_vector_type(4)));

#define EDGE_DIM 64
#define NODE_DIM 128
#define XDIM 192     // logical MLP K: agg(64) | nodes(128)
#define HID_DIM 256
#define OUT_DIM 128
#define NBUCKET 2048
#define NPB 25       // nodes per bucket: 2048*25 = 51200 >= 50000; local < 32 (5 bits)
#define CAP 1024     // bucket capacity (mean 781, sigma ~28 -> 8.7 sigma margin)
#define EPB 4096     // edges per scatter block (256 thr x 16) — measured optimum
#define MT 64        // M-tile of MLP
#define HPAD 280     // Hs row stride (bf16)

// ---------------- K1: weight prep (+bias fold) + gcur init ------------------
__global__ __launch_bounds__(256) void prep_kernel(
    const float* __restrict__ W1, const float* __restrict__ b1,
    const float* __restrict__ W2, const float* __restrict__ glob,
    __bf16* __restrict__ W1T, float* __restrict__ b1f, __bf16* __restrict__ W2T,
    int* __restrict__ gcur) {
  const int b = blockIdx.x, t = threadIdx.x;
  if (b < HID_DIM) {
    if (t < XDIM) {
      W1T[b * XDIM + t] = (__bf16)W1[t * HID_DIM + b];
    } else {
      // threads 192..255 == wave 3: fold globals into bias (f32 exact)
      float p = glob[t - XDIM] * W1[t * HID_DIM + b];
      for (int off = 32; off; off >>= 1) p += __shfl_xor(p, off, 64);
      if (t == XDIM) b1f[b] = b1[b] + p;
    }
    return;
  }
  if (b < HID_DIM + OUT_DIM) {
    int nn = b - HID_DIM;
    W2T[nn * HID_DIM + t] = (__bf16)W2[t * OUT_DIM + nn];
    return;
  }
  // b == HID_DIM + OUT_DIM: init bucket cursors to fixed bases
  for (int k = t; k < NBUCKET; k += 256) gcur[k] = k * CAP;
}

// ---------------- K2: fused count + reserve + scatter -----------------------
__global__ __launch_bounds__(256) void scatter_kernel(
    const int* __restrict__ recv, int* __restrict__ gcur,
    int* __restrict__ sorted1, int n_edges) {
  const int kb = blockIdx.x, t = threadIdx.x;
  __shared__ int h[NBUCKET];  // pass 1: counts; pass 2: cursors (8 KB)
  for (int k = t; k < NBUCKET; k += 256) h[k] = 0;
  __syncthreads();

  const int i0 = kb * EPB + t * 16;
  int rr[16];
  int bk[16];
  if (i0 + 16 <= n_edges) {
#pragma unroll
    for (int c = 0; c < 4; ++c) {
      i32x4 r4 = *(const i32x4*)(recv + i0 + c * 4);
      rr[c * 4 + 0] = r4.x; rr[c * 4 + 1] = r4.y;
      rr[c * 4 + 2] = r4.z; rr[c * 4 + 3] = r4.w;
    }
  } else {
#pragma unroll
    for (int j = 0; j < 16; ++j) rr[j] = (i0 + j < n_edges) ? recv[i0 + j] : -1;
  }
#pragma unroll
  for (int j = 0; j < 16; ++j) {
    bk[j] = (rr[j] >= 0) ? (rr[j] / NPB) : -1;
    if (bk[j] >= 0) atomicAdd(&h[bk[j]], 1);
  }
  __syncthreads();

  // reserve this block's segment in each touched bucket (global atomic)
  for (int k = t; k < NBUCKET; k += 256) {
    int c = h[k];
    h[k] = (c > 0) ? atomicAdd(&gcur[k], c) : 0;  // overwrite count with base
  }
  __syncthreads();

  // scatter: cursor = LDS base, packed payload (eid<<5)|local
#pragma unroll
  for (int j = 0; j < 16; ++j) {
    if (bk[j] >= 0) {
      const int p = atomicAdd(&h[bk[j]], 1);
      sorted1[p] = ((i0 + j) << 5) | (rr[j] - bk[j] * NPB);
    }
  }
}

// ---------------- K3: FUSED regroup (LDS) + quarter-wave gather -------------
#define NTLOAD(i) __builtin_nontemporal_load((const f32x4*)(edges + (size_t)(i) * EDGE_DIM + l15 * 4))

__global__ __launch_bounds__(256) void regroup_gather_kernel(
    const int* __restrict__ sorted1, const int* __restrict__ gcur,
    const float* __restrict__ edges,
    __bf16* __restrict__ Xagg, int n_nodes) {
  const int b = blockIdx.x, t = threadIdx.x;
  __shared__ int eidl[CAP];      // 4 KB: per-node-grouped eids (bucket-local)
  __shared__ int loff[NPB + 1];
  __shared__ int cnt[NPB];
  if (t < NPB) cnt[t] = 0;
  __syncthreads();
  const int s = b * CAP, e = gcur[b];  // gcur holds bucket end
  // phase A1: count locals
  for (int j = s + t; j < e; j += 256) atomicAdd(&cnt[sorted1[j] & 31], 1);
  __syncthreads();
  if (t == 0) {
    int run = 0;
#pragma unroll
    for (int k = 0; k < NPB; ++k) { loff[k] = run; run += cnt[k]; }
    loff[NPB] = run;
  }
  __syncthreads();
  if (t < NPB) cnt[t] = 0;  // reuse as cursor
  __syncthreads();
  // phase A2: group eids into LDS
  for (int j = s + t; j < e; j += 256) {
    const int p = sorted1[j];
    const int local = p & 31;
    const int slot = atomicAdd(&cnt[local], 1);
    eidl[loff[local] + slot] = p >> 5;
  }
  __syncthreads();

  // phase B: gather — wave w owns locals w, w+4, ... (proven 4-deep pipeline)
  const int wave = t >> 6;
  const int lane = t & 63;
  const int q = lane >> 4;
  const int l15 = lane & 15;
  for (int local = wave; local < NPB; local += 4) {
    const int node = b * NPB + local;
    if (node >= n_nodes) break;
    const int ls = loff[local];
    const int le = loff[local + 1];
    f32x4 a0 = {0.f, 0.f, 0.f, 0.f}, a1 = a0, a2 = a0, a3 = a0;

    int j = ls + q;
    int i0 = (j < le) ? eidl[j] : 0;
    int i1 = (j + 4 < le) ? eidl[j + 4] : 0;
    int i2 = (j + 8 < le) ? eidl[j + 8] : 0;
    int i3 = (j + 12 < le) ? eidl[j + 12] : 0;

    while (j + 12 < le) {
      f32x4 v0 = NTLOAD(i0);
      f32x4 v1 = NTLOAD(i1);
      f32x4 v2 = NTLOAD(i2);
      f32x4 v3 = NTLOAD(i3);
      int n0 = (j + 16 < le) ? eidl[j + 16] : 0;
      int n1 = (j + 20 < le) ? eidl[j + 20] : 0;
      int n2 = (j + 24 < le) ? eidl[j + 24] : 0;
      int n3 = (j + 28 < le) ? eidl[j + 28] : 0;
      a0 += v0; a1 += v1; a2 += v2; a3 += v3;
      i0 = n0; i1 = n1; i2 = n2; i3 = n3;
      j += 16;
    }
    if (j < le)     a0 += NTLOAD(i0);
    if (j + 4 < le) a1 += NTLOAD(i1);
    if (j + 8 < le) a2 += NTLOAD(i2);

    a0 += a1; a2 += a3; a0 += a2;
#pragma unroll
    for (int c = 0; c < 4; ++c) {  // reduce across the 4 quarters
      float v = a0[c];
      v += __shfl_xor(v, 16, 64);
      v += __shfl_xor(v, 32, 64);
      a0[c] = v;
    }
    if (q == 0) {
      bf16x4 o;
      o[0] = (__bf16)a0[0]; o[1] = (__bf16)a0[1];
      o[2] = (__bf16)a0[2]; o[3] = (__bf16)a0[3];
      *(bf16x4*)(Xagg + (size_t)node * EDGE_DIM + l15 * 4) = o;  // 8B store
    }
  }
}

// ---------------- K4: fused MLP (nodes read direct, f32->bf16 in-reg) -------
__global__ __launch_bounds__(256, 2) void mlp_kernel(
    const __bf16* __restrict__ Xagg, const float* __restrict__ nodes,
    const __bf16* __restrict__ W1T, const float* __restrict__ b1f,
    const __bf16* __restrict__ W2T, const float* __restrict__ b2,
    float* __restrict__ out, int M) {
  __shared__ __bf16 Hs[MT][HPAD];
  const int wave = threadIdx.x >> 6;
  const int lane = threadIdx.x & 63;
  const int l15 = lane & 15;
  const int lk = lane >> 4;
  const int Mbase0 = blockIdx.x * MT;

  {  // phase 1: H = relu([Xagg|nodes] @ W1[:192] + b1') -> LDS (K=192)
    bf16x8 B1[4][6];
    float bias1[4];
    const int colbase = wave * 64;
#pragma unroll
    for (int cb = 0; cb < 4; ++cb) {
      const int col = colbase + cb * 16 + l15;
      const __bf16* wrow = W1T + col * XDIM + lk * 8;
#pragma unroll
      for (int ks = 0; ks < 6; ++ks) B1[cb][ks] = *(const bf16x8*)(wrow + ks * 32);
      bias1[cb] = b1f[col];
    }
#pragma unroll
    for (int mb = 0; mb < 4; ++mb) {
      const int Mbase = Mbase0 + mb * 16;
      const int arow = (Mbase + l15 < M) ? (Mbase + l15) : (M - 1);  // clamp
      f32x4 acc[4];
#pragma unroll
      for (int cb = 0; cb < 4; ++cb) {
        f32x4 ini = {bias1[cb], bias1[cb], bias1[cb], bias1[cb]};
        acc[cb] = ini;
      }
      const __bf16* xrow = Xagg + (size_t)arow * EDGE_DIM + lk * 8;
      const float* nrow = nodes + (size_t)arow * NODE_DIM + lk * 8;
      // ks 0..1: agg fragment from Xagg (bf16)
#pragma unroll
      for (int ks = 0; ks < 2; ++ks) {
        bf16x8 A = *(const bf16x8*)(xrow + ks * 32);
#pragma unroll
        for (int cb = 0; cb < 4; ++cb)
          acc[cb] = __builtin_amdgcn_mfma_f32_16x16x32_bf16(A, B1[cb][ks], acc[cb], 0, 0, 0);
      }
      // ks 2..5: node fragment from nodes (f32 -> bf16 in-register)
#pragma unroll
      for (int ks = 2; ks < 6; ++ks) {
        f32x4 n0 = *(const f32x4*)(nrow + (ks - 2) * 32);
        f32x4 n1 = *(const f32x4*)(nrow + (ks - 2) * 32 + 4);
        bf16x8 A;
        A[0] = (__bf16)n0[0]; A[1] = (__bf16)n0[1];
        A[2] = (__bf16)n0[2]; A[3] = (__bf16)n0[3];
        A[4] = (__bf16)n1[0]; A[5] = (__bf16)n1[1];
        A[6] = (__bf16)n1[2]; A[7] = (__bf16)n1[3];
#pragma unroll
        for (int cb = 0; cb < 4; ++cb)
          acc[cb] = __builtin_amdgcn_mfma_f32_16x16x32_bf16(A, B1[cb][ks], acc[cb], 0, 0, 0);
      }
#pragma unroll
      for (int cb = 0; cb < 4; ++cb) {
#pragma unroll
        for (int r = 0; r < 4; ++r) {
          float v = acc[cb][r];
          Hs[mb * 16 + lk * 4 + r][colbase + cb * 16 + l15] = (__bf16)(v > 0.f ? v : 0.f);
        }
      }
    }
  }
  __syncthreads();
  {  // phase 2: out = H @ W2 + b2
    bf16x8 B2[2][8];
    float bias2[2];
    const int colbase = wave * 32;
#pragma unroll
    for (int cb = 0; cb < 2; ++cb) {
      const int col = colbase + cb * 16 + l15;
      const __bf16* wrow = W2T + col * HID_DIM + lk * 8;
#pragma unroll
      for (int ks = 0; ks < 8; ++ks) B2[cb][ks] = *(const bf16x8*)(wrow + ks * 32);
      bias2[cb] = b2[col];
    }
#pragma unroll
    for (int mb = 0; mb < 4; ++mb) {
      const int Mbase = Mbase0 + mb * 16;
      f32x4 acc[2];
#pragma unroll
      for (int cb = 0; cb < 2; ++cb) {
        f32x4 ini = {bias2[cb], bias2[cb], bias2[cb], bias2[cb]};
        acc[cb] = ini;
      }
#pragma unroll
      for (int ks = 0; ks < 8; ++ks) {
        bf16x8 A = *(const bf16x8*)(&Hs[mb * 16 + l15][lk * 8 + ks * 32]);
#pragma unroll
        for (int cb = 0; cb < 2; ++cb)
          acc[cb] = __builtin_amdgcn_mfma_f32_16x16x32_bf16(A, B2[cb][ks], acc[cb], 0, 0, 0);
      }
#pragma unroll
      for (int cb = 0; cb < 2; ++cb) {
        const int col = colbase + cb * 16 + l15;
#pragma unroll
        for (int r = 0; r < 4; ++r) {
          const int row = Mbase + lk * 4 + r;
          if (row < M) out[(size_t)row * OUT_DIM + col] = acc[cb][r];
        }
      }
    }
  }
}

extern "C" void kernel_launch(void* const* d_in, const int* in_sizes, int n_in,
                              void* d_out, int out_size, void* d_ws, size_t ws_size,
                              hipStream_t stream) {
  const float* edges    = (const float*)d_in[0];
  const int*   recv     = (const int*)d_in[1];
  const float* nodes    = (const float*)d_in[2];
  const float* globals_ = (const float*)d_in[3];
  const float* W1       = (const float*)d_in[5];
  const float* b1       = (const float*)d_in[6];
  const float* W2       = (const float*)d_in[7];
  const float* b2       = (const float*)d_in[8];

  const int n_edges = in_sizes[0] / EDGE_DIM;  // 1600000
  const int n_nodes = in_sizes[2] / NODE_DIM;  // 50000
  const int NBH = (n_edges + EPB - 1) / EPB;   // 391 scatter blocks
  float* out = (float*)d_out;

  // workspace layout (~15 MB)
  char* ws = (char*)d_ws;
  size_t off = 0;
  int* gcur = (int*)(ws + off);    off += NBUCKET * 4;
  off = (off + 255) & ~(size_t)255;
  int* sorted1 = (int*)(ws + off); off += (size_t)NBUCKET * CAP * 4;  // 8 MB
  off = (off + 255) & ~(size_t)255;
  __bf16* Xagg = (__bf16*)(ws + off); off += (size_t)n_nodes * EDGE_DIM * 2;  // 6.4 MB
  off = (off + 255) & ~(size_t)255;
  __bf16* W1T = (__bf16*)(ws + off); off += (size_t)HID_DIM * XDIM * 2;
  off = (off + 255) & ~(size_t)255;
  float* b1f = (float*)(ws + off);  off += HID_DIM * 4;
  off = (off + 255) & ~(size_t)255;
  __bf16* W2T = (__bf16*)(ws + off); off += (size_t)HID_DIM * OUT_DIM * 2;

  prep_kernel<<<HID_DIM + OUT_DIM + 1, 256, 0, stream>>>(
      W1, b1, W2, globals_, W1T, b1f, W2T, gcur);
  scatter_kernel<<<NBH, 256, 0, stream>>>(recv, gcur, sorted1, n_edges);
  regroup_gather_kernel<<<NBUCKET, 256, 0, stream>>>(sorted1, gcur, edges,
                                                     Xagg, n_nodes);
  mlp_kernel<<<(n_nodes + MT - 1) / MT, 256, 0, stream>>>(Xagg, nodes, W1T, b1f,
                                                          W2T, b2, out, n_nodes);
}